// Round 24
// baseline (2647.339 us; speedup 1.0000x reference)
//
#include <hip/hip_runtime.h>

#define B 8
#define N 16384
#define NPOINT 1024
#define NSAMPLE 32
#define CDIM 128
#define CELLS 4096

// d_out layout (floats), reference return order:
// new_xyz [B,NPOINT,3], new_points [B,NPOINT,NSAMPLE,CDIM], idx [B,NPOINT,NSAMPLE], grouped_xyz [B,NPOINT,NSAMPLE,3]
#define OFF_NEWXYZ 0
#define OFF_NEWPTS (B * NPOINT * 3)                           // 24576
#define OFF_IDX    (OFF_NEWPTS + B * NPOINT * NSAMPLE * CDIM) // 33579008
#define OFF_GXYZ   (OFF_IDX + B * NPOINT * NSAMPLE)           // 33841152

typedef unsigned long long u64;

// u64-min DPP step: both halves shift coherently; invalid lanes keep old -> identity.
// row_shr:N operates WITHIN each 16-lane DPP row.
template <int CTRL>
__device__ __forceinline__ u64 mindpp_u64(u64 k) {
    const int lo = (int)(unsigned)(k & 0xffffffffull);
    const int hi = (int)(unsigned)(k >> 32);
    const int lo2 = __builtin_amdgcn_update_dpp(lo, lo, CTRL, 0xf, 0xf, false);
    const int hi2 = __builtin_amdgcn_update_dpp(hi, hi, CTRL, 0xf, 0xf, false);
    const u64 kt = ((u64)(unsigned)hi2 << 32) | (unsigned)lo2;
    return kt < k ? kt : k;
}

__device__ __forceinline__ int spread3(int v) {   // 4-bit -> bits 0,3,6,9
    return (v & 1) | ((v & 2) << 2) | ((v & 4) << 4) | ((v & 8) << 6);
}

// ---------- sort: Morton-bin each batch into AoS (x,y,z,(float)n) ----------
// Intra-cell order nondeterministic (atomicAdd) — harmless: all downstream
// reductions are (max d, min orig-n) exact, independent of storage order.
__global__ __launch_bounds__(1024) void sort_kernel(const float* __restrict__ xyz,
                                                    float* __restrict__ sorted) {
    const int b = blockIdx.x;
    const int t = threadIdx.x;
    const float* xb = xyz + (size_t)b * N * 3;

    __shared__ unsigned int hist[CELLS];     // 16 KiB
    __shared__ unsigned int waveS[16];

#pragma unroll
    for (int i = 0; i < CELLS / 1024; ++i) hist[i * 1024 + t] = 0;
    __syncthreads();

    int cell[16];
#pragma unroll
    for (int k = 0; k < 16; ++k) {
        const int n = k * 1024 + t;
        const float x = xb[n * 3 + 0];
        const float y = xb[n * 3 + 1];
        const float z = xb[n * 3 + 2];
        int cx = (int)(x * 16.0f); cx = cx < 0 ? 0 : (cx > 15 ? 15 : cx);
        int cy = (int)(y * 16.0f); cy = cy < 0 ? 0 : (cy > 15 ? 15 : cy);
        int cz = (int)(z * 16.0f); cz = cz < 0 ? 0 : (cz > 15 ? 15 : cz);
        cell[k] = spread3(cx) | (spread3(cy) << 1) | (spread3(cz) << 2);
        atomicAdd(&hist[cell[k]], 1u);
    }
    __syncthreads();

    const unsigned h0 = hist[4 * t + 0], h1 = hist[4 * t + 1],
                   h2 = hist[4 * t + 2], h3 = hist[4 * t + 3];
    const unsigned sum4 = h0 + h1 + h2 + h3;
    const int wid = t >> 6, lane = t & 63;
    unsigned inc = sum4;
#pragma unroll
    for (int off = 1; off < 64; off <<= 1) {
        const unsigned v = __shfl_up(inc, off);
        if (lane >= off) inc += v;
    }
    if (lane == 63) waveS[wid] = inc;
    __syncthreads();
    unsigned wbase = 0;
    {
        unsigned ws = (lane < 16) ? waveS[lane] : 0u;
        unsigned wi = ws;
#pragma unroll
        for (int off = 1; off < 16; off <<= 1) {
            const unsigned v = __shfl_up(wi, off);
            if (lane >= off) wi += v;
        }
        wbase = __shfl(wi - ws, wid);
    }
    const unsigned base = wbase + (inc - sum4);
    __syncthreads();
    hist[4 * t + 0] = base;
    hist[4 * t + 1] = base + h0;
    hist[4 * t + 2] = base + h0 + h1;
    hist[4 * t + 3] = base + h0 + h1 + h2;
    __syncthreads();

    float4* sb = (float4*)sorted + (size_t)b * N;
#pragma unroll
    for (int k = 0; k < 16; ++k) {
        const int n = k * 1024 + t;
        const float x = xb[n * 3 + 0];
        const float y = xb[n * 3 + 1];
        const float z = xb[n * 3 + 2];
        const unsigned pos = atomicAdd(&hist[cell[k]], 1u);
        sb[pos] = make_float4(x, y, z, (float)n);
    }
}

// ------- FPS: 2 batches per block — cross-batch ILP fills latency gaps -------
// r18's shared-queue compaction per batch, but each block runs TWO independent
// batches in lockstep: every phase has two independent instruction streams
// (dual s_loads, dual B-loops, dual DPP chains) and the 3 barriers/step are
// shared. Exact (max d, min orig-n) tie-break via u64-min keys
// (~bits(d)<<14 | n). Skip test: bbox-dist^2 > mval*1.0001 (sound; chosen
// centroid's owner has md2=0 -> always executes).
__global__ __launch_bounds__(1024) void fps_kernel(const float* __restrict__ xyz,
                                                   const float* __restrict__ sorted,
                                                   float* out) {
#pragma clang fp contract(off)
    const int b0 = blockIdx.x * 2;
    const int b1 = b0 + 1;
    const int t = threadIdx.x;
    const float* xb0 = xyz + (size_t)b0 * N * 3;
    const float* xb1 = xyz + (size_t)b1 * N * 3;
    const float4* sb0 = (const float4*)sorted + (size_t)b0 * N;
    const float4* sb1 = (const float4*)sorted + (size_t)b1 * N;

    __shared__ float sd0[N];                  // 64 KiB
    __shared__ float sd1[N];                  // 64 KiB
    __shared__ u64 segkey0[1024];             // 8 KiB
    __shared__ u64 segkey1[1024];             // 8 KiB
    __shared__ unsigned short queue0[1024];   // 2 KiB
    __shared__ unsigned short queue1[1024];   // 2 KiB
    __shared__ unsigned qc[2][2];
    __shared__ u64 swkey0[2][16];
    __shared__ u64 swkey1[2][16];

    const int wid = t >> 6;
    const int lane = t & 63;

    float lox0 = 1e30f, hix0 = -1e30f, loy0 = 1e30f, hiy0 = -1e30f, loz0 = 1e30f, hiz0 = -1e30f;
    float lox1 = 1e30f, hix1 = -1e30f, loy1 = 1e30f, hiy1 = -1e30f, loz1 = 1e30f, hiz1 = -1e30f;
#pragma unroll
    for (int k = 0; k < 16; ++k) {
        const float4 v0 = sb0[t * 16 + k];
        const float4 v1 = sb1[t * 16 + k];
        lox0 = fminf(lox0, v0.x); hix0 = fmaxf(hix0, v0.x);
        loy0 = fminf(loy0, v0.y); hiy0 = fmaxf(hiy0, v0.y);
        loz0 = fminf(loz0, v0.z); hiz0 = fmaxf(hiz0, v0.z);
        lox1 = fminf(lox1, v1.x); hix1 = fmaxf(hix1, v1.x);
        loy1 = fminf(loy1, v1.y); hiy1 = fmaxf(hiy1, v1.y);
        loz1 = fminf(loz1, v1.z); hiz1 = fmaxf(hiz1, v1.z);
        sd0[t * 16 + k] = 1e10f;
        sd1[t * 16 + k] = 1e10f;
    }
    if (t == 0) { qc[0][0] = 0; qc[0][1] = 0; qc[1][0] = 0; qc[1][1] = 0; }
    u64 rkey0 = ~0ull, rkey1 = ~0ull;
    float mval0 = 1e10f, mval1 = 1e10f;      // force ex at s=0
    __syncthreads();

    float* nxo0 = out + OFF_NEWXYZ + (size_t)b0 * NPOINT * 3;
    float* nxo1 = out + OFF_NEWXYZ + (size_t)b1 * NPOINT * 3;
    int far0 = 0, far1 = 0;

    for (int s = 0; s < NPOINT; ++s) {
        const int fs0 = __builtin_amdgcn_readfirstlane(far0);
        const int fs1 = __builtin_amdgcn_readfirstlane(far1);
        const float cx0 = xb0[fs0 * 3 + 0];
        const float cy0 = xb0[fs0 * 3 + 1];
        const float cz0 = xb0[fs0 * 3 + 2];
        const float cx1 = xb1[fs1 * 3 + 0];
        const float cy1 = xb1[fs1 * 3 + 1];
        const float cz1 = xb1[fs1 * 3 + 2];
        if (t == 0) {
            nxo0[s * 3 + 0] = cx0;
            nxo0[s * 3 + 1] = cy0;
            nxo0[s * 3 + 2] = cz0;
            nxo1[s * 3 + 0] = cx1;
            nxo1[s * 3 + 1] = cy1;
            nxo1[s * 3 + 2] = cz1;
        }
        if (s == NPOINT - 1) break;                  // last argmax is discarded

        // ---- A: dual bbox tests + dual ballot enqueue ----
        const float ax0 = fmaxf(fmaxf(__fsub_rn(lox0, cx0), __fsub_rn(cx0, hix0)), 0.0f);
        const float ay0 = fmaxf(fmaxf(__fsub_rn(loy0, cy0), __fsub_rn(cy0, hiy0)), 0.0f);
        const float az0 = fmaxf(fmaxf(__fsub_rn(loz0, cz0), __fsub_rn(cz0, hiz0)), 0.0f);
        const float md20 = __fadd_rn(__fadd_rn(__fmul_rn(ax0, ax0), __fmul_rn(ay0, ay0)),
                                     __fmul_rn(az0, az0));
        const bool ex0 = !(md20 > __fmul_rn(mval0, 1.0001f));
        const float ax1 = fmaxf(fmaxf(__fsub_rn(lox1, cx1), __fsub_rn(cx1, hix1)), 0.0f);
        const float ay1 = fmaxf(fmaxf(__fsub_rn(loy1, cy1), __fsub_rn(cy1, hiy1)), 0.0f);
        const float az1 = fmaxf(fmaxf(__fsub_rn(loz1, cz1), __fsub_rn(cz1, hiz1)), 0.0f);
        const float md21 = __fadd_rn(__fadd_rn(__fmul_rn(ax1, ax1), __fmul_rn(ay1, ay1)),
                                     __fmul_rn(az1, az1));
        const bool ex1 = !(md21 > __fmul_rn(mval1, 1.0001f));
        if (t == 0) { qc[(s + 1) & 1][0] = 0; qc[(s + 1) & 1][1] = 0; }
        {
            const u64 bal0 = __ballot(ex0);
            unsigned wb0 = 0;
            if (lane == 0) wb0 = atomicAdd(&qc[s & 1][0], (unsigned)__popcll(bal0));
            wb0 = __shfl(wb0, 0);
            if (ex0) {
                const unsigned pos = wb0 + (unsigned)__popcll(bal0 & ((1ull << lane) - 1ull));
                queue0[pos] = (unsigned short)t;
            }
            const u64 bal1 = __ballot(ex1);
            unsigned wb1 = 0;
            if (lane == 0) wb1 = atomicAdd(&qc[s & 1][1], (unsigned)__popcll(bal1));
            wb1 = __shfl(wb1, 0);
            if (ex1) {
                const unsigned pos = wb1 + (unsigned)__popcll(bal1 & ((1ull << lane) - 1ull));
                queue1[pos] = (unsigned short)t;
            }
        }
        __syncthreads();

        // ---- B: dual packed segment processing (16-lane row per segment) ----
        const unsigned nseg0 = qc[s & 1][0];
        const unsigned nseg1 = qc[s & 1][1];
        const int row = t >> 4;
        const int col = t & 15;
        for (unsigned j = (unsigned)row; j < nseg0; j += 64) {
            const int seg = queue0[j];
            const int p = (seg << 4) | col;
            const float4 v = sb0[p];
            const float dx = __fsub_rn(v.x, cx0);
            const float dy = __fsub_rn(v.y, cy0);
            const float dz = __fsub_rn(v.z, cz0);
            const float dist = __fadd_rn(
                __fadd_rn(__fmul_rn(dx, dx), __fmul_rn(dy, dy)),
                __fmul_rn(dz, dz));
            const float dnew = fminf(sd0[p], dist);
            sd0[p] = dnew;
            u64 key = ((u64)(unsigned)(~__float_as_uint(dnew)) << 14) |
                      (unsigned)(int)v.w;
            key = mindpp_u64<0x111>(key);
            key = mindpp_u64<0x112>(key);
            key = mindpp_u64<0x114>(key);
            key = mindpp_u64<0x118>(key);   // lane 15 of row = row min
            if (col == 15) segkey0[seg] = key;
        }
        for (unsigned j = (unsigned)row; j < nseg1; j += 64) {
            const int seg = queue1[j];
            const int p = (seg << 4) | col;
            const float4 v = sb1[p];
            const float dx = __fsub_rn(v.x, cx1);
            const float dy = __fsub_rn(v.y, cy1);
            const float dz = __fsub_rn(v.z, cz1);
            const float dist = __fadd_rn(
                __fadd_rn(__fmul_rn(dx, dx), __fmul_rn(dy, dy)),
                __fmul_rn(dz, dz));
            const float dnew = fminf(sd1[p], dist);
            sd1[p] = dnew;
            u64 key = ((u64)(unsigned)(~__float_as_uint(dnew)) << 14) |
                      (unsigned)(int)v.w;
            key = mindpp_u64<0x111>(key);
            key = mindpp_u64<0x112>(key);
            key = mindpp_u64<0x114>(key);
            key = mindpp_u64<0x118>(key);
            if (col == 15) segkey1[seg] = key;
        }
        __syncthreads();

        // ---- C: dual refresh + dual DPP wave reduce (independent chains) ----
        if (ex0) {
            const u64 rk = segkey0[t];
            rkey0 = rk;
            mval0 = __uint_as_float(~(unsigned)(rk >> 14));
        }
        if (ex1) {
            const u64 rk = segkey1[t];
            rkey1 = rk;
            mval1 = __uint_as_float(~(unsigned)(rk >> 14));
        }
        u64 k0 = rkey0, k1 = rkey1;
        k0 = mindpp_u64<0x111>(k0);  k1 = mindpp_u64<0x111>(k1);
        k0 = mindpp_u64<0x112>(k0);  k1 = mindpp_u64<0x112>(k1);
        k0 = mindpp_u64<0x114>(k0);  k1 = mindpp_u64<0x114>(k1);
        k0 = mindpp_u64<0x118>(k0);  k1 = mindpp_u64<0x118>(k1);
        k0 = mindpp_u64<0x142>(k0);  k1 = mindpp_u64<0x142>(k1);
        k0 = mindpp_u64<0x143>(k0);  k1 = mindpp_u64<0x143>(k1);
        if (lane == 63) {
            swkey0[s & 1][wid] = k0;
            swkey1[s & 1][wid] = k1;
        }
        __syncthreads();
        u64 kk0 = swkey0[s & 1][lane & 15];
        u64 kk1 = swkey1[s & 1][lane & 15];
        kk0 = mindpp_u64<0x111>(kk0);  kk1 = mindpp_u64<0x111>(kk1);
        kk0 = mindpp_u64<0x112>(kk0);  kk1 = mindpp_u64<0x112>(kk1);
        kk0 = mindpp_u64<0x114>(kk0);  kk1 = mindpp_u64<0x114>(kk1);
        kk0 = mindpp_u64<0x118>(kk0);  kk1 = mindpp_u64<0x118>(kk1);
        far0 = __builtin_amdgcn_readlane((int)(unsigned)(kk0 & 0xffffffffull), 15) & 16383;
        far1 = __builtin_amdgcn_readlane((int)(unsigned)(kk1 & 0xffffffffull), 15) & 16383;
    }
}

// ---------------- Ball query: one 64-lane wave per centroid ----------------
__global__ __launch_bounds__(256) void ballq_kernel(const float* __restrict__ xyz,
                                                    const float* __restrict__ radius_p,
                                                    float* out) {
    const int wib = threadIdx.x >> 6;
    const int lane = threadIdx.x & 63;
    const int gw = blockIdx.x * 4 + wib;   // 0..8191
    const int b = gw >> 10;
    const int s = gw & 1023;

    const float r = radius_p[0];
    const float r2 = __fmul_rn(r, r);

    const float* xb = xyz + (size_t)b * N * 3;
    const float* nx = out + OFF_NEWXYZ + (size_t)(b * NPOINT + s) * 3;
    const float c0 = nx[0], c1 = nx[1], c2 = nx[2];
    const float ss_s = __fadd_rn(__fadd_rn(__fmul_rn(c0, c0), __fmul_rn(c1, c1)),
                                 __fmul_rn(c2, c2));

    float* oidx = out + OFF_IDX + (size_t)(b * NPOINT + s) * NSAMPLE;
    float* ogx  = out + OFF_GXYZ + (size_t)(b * NPOINT + s) * NSAMPLE * 3;

    int filled = 0;
    int first = -1;
    for (int n0 = 0; n0 < N; n0 += 64) {
        const int n = n0 + lane;
        const float x = xb[n * 3 + 0];
        const float y = xb[n * 3 + 1];
        const float z = xb[n * 3 + 2];
        const float ssx = __fadd_rn(__fadd_rn(__fmul_rn(x, x), __fmul_rn(y, y)),
                                    __fmul_rn(z, z));
        const float dot = __fadd_rn(__fadd_rn(__fmul_rn(c0, x), __fmul_rn(c1, y)),
                                    __fmul_rn(c2, z));
        const float d2 = __fsub_rn(__fadd_rn(ss_s, ssx), __fmul_rn(2.0f, dot));
        const bool in = d2 < r2;
        const unsigned long long m = __ballot(in);
        if (first < 0 && m != 0ull) first = n0 + (int)__builtin_ctzll(m);
        if (in) {
            const int pos = filled + (int)__popcll(m & ((1ull << lane) - 1ull));
            if (pos < NSAMPLE) {
                oidx[pos] = (float)n;
                ogx[pos * 3 + 0] = __fsub_rn(x, c0);
                ogx[pos * 3 + 1] = __fsub_rn(y, c1);
                ogx[pos * 3 + 2] = __fsub_rn(z, c2);
            }
        }
        filled += (int)__popcll(m);
        if (filled >= NSAMPLE) break;
    }
    if (filled < NSAMPLE) {
        if (first < 0) first = 0;
        const float fx = xb[first * 3 + 0];
        const float fy = xb[first * 3 + 1];
        const float fz = xb[first * 3 + 2];
        const float g0 = __fsub_rn(fx, c0);
        const float g1 = __fsub_rn(fy, c1);
        const float g2 = __fsub_rn(fz, c2);
        for (int pos = filled + lane; pos < NSAMPLE; pos += 64) {
            oidx[pos] = (float)first;
            ogx[pos * 3 + 0] = g0;
            ogx[pos * 3 + 1] = g1;
            ogx[pos * 3 + 2] = g2;
        }
    }
}

// ---------------- new_points gather: one block per (b,s) ----------------
__global__ __launch_bounds__(256) void gather_kernel(const float* __restrict__ points,
                                                     float* out) {
    const int blk = blockIdx.x;            // b*NPOINT + s
    const int w = threadIdx.x >> 6;
    const int lane = threadIdx.x & 63;
    const int b = blk >> 10;

    const float* oidx = out + OFF_IDX + (size_t)blk * NSAMPLE;
    const float* pb = points + (size_t)b * N * CDIM;
    float* onp = out + OFF_NEWPTS + (size_t)blk * NSAMPLE * CDIM;

#pragma unroll
    for (int i = 0; i < 8; ++i) {
        const int slot = w * 8 + i;
        const int n = (int)oidx[slot];
        const float2 v = *(const float2*)(pb + (size_t)n * CDIM + lane * 2);
        *(float2*)(onp + (size_t)slot * CDIM + lane * 2) = v;
    }
}

extern "C" void kernel_launch(void* const* d_in, const int* in_sizes, int n_in,
                              void* d_out, int out_size, void* d_ws, size_t ws_size,
                              hipStream_t stream) {
    // inputs: [0]=npoint(int,1), [1]=radius(f32,1), [2]=xyz(f32, B*N*3), [3]=points(f32, B*N*CDIM)
    const float* xyz = (const float*)d_in[2];
    const float* points = (const float*)d_in[3];
    const float* radius = (const float*)d_in[1];
    float* out = (float*)d_out;

    // sorted AoS scratch lives in the new_points output region (2 MB of 134 MB);
    // gather_kernel fully overwrites it afterwards.
    float* sorted = out + OFF_NEWPTS;

    hipLaunchKernelGGL(sort_kernel, dim3(B), dim3(1024), 0, stream, xyz, sorted);
    hipLaunchKernelGGL(fps_kernel, dim3(B / 2), dim3(1024), 0, stream, xyz, sorted, out);
    hipLaunchKernelGGL(ballq_kernel, dim3((B * NPOINT) / 4), dim3(256), 0, stream, xyz, radius, out);
    hipLaunchKernelGGL(gather_kernel, dim3(B * NPOINT), dim3(256), 0, stream, points, out);
}

// Round 25
// 1522.134 us; speedup vs baseline: 1.7392x; 1.7392x over previous
//
#include <hip/hip_runtime.h>

#define B 8
#define N 16384
#define NPOINT 1024
#define NSAMPLE 32
#define CDIM 128
#define CELLS 4096

// d_out layout (floats), reference return order:
// new_xyz [B,NPOINT,3], new_points [B,NPOINT,NSAMPLE,CDIM], idx [B,NPOINT,NSAMPLE], grouped_xyz [B,NPOINT,NSAMPLE,3]
#define OFF_NEWXYZ 0
#define OFF_NEWPTS (B * NPOINT * 3)                           // 24576
#define OFF_IDX    (OFF_NEWPTS + B * NPOINT * NSAMPLE * CDIM) // 33579008
#define OFF_GXYZ   (OFF_IDX + B * NPOINT * NSAMPLE)           // 33841152

typedef unsigned long long u64;

// u64-min DPP step: both halves shift coherently; invalid lanes keep old -> identity.
// row_shr:N operates WITHIN each 16-lane DPP row.
template <int CTRL>
__device__ __forceinline__ u64 mindpp_u64(u64 k) {
    const int lo = (int)(unsigned)(k & 0xffffffffull);
    const int hi = (int)(unsigned)(k >> 32);
    const int lo2 = __builtin_amdgcn_update_dpp(lo, lo, CTRL, 0xf, 0xf, false);
    const int hi2 = __builtin_amdgcn_update_dpp(hi, hi, CTRL, 0xf, 0xf, false);
    const u64 kt = ((u64)(unsigned)hi2 << 32) | (unsigned)lo2;
    return kt < k ? kt : k;
}

__device__ __forceinline__ int spread3(int v) {   // 4-bit -> bits 0,3,6,9
    return (v & 1) | ((v & 2) << 2) | ((v & 4) << 4) | ((v & 8) << 6);
}

// ---------- sort: Morton-bin each batch into AoS (x,y,z,(float)n) ----------
// Intra-cell order nondeterministic (atomicAdd) — harmless: all downstream
// reductions are (max d, min orig-n) exact, independent of storage order.
__global__ __launch_bounds__(1024) void sort_kernel(const float* __restrict__ xyz,
                                                    float* __restrict__ sorted) {
    const int b = blockIdx.x;
    const int t = threadIdx.x;
    const float* xb = xyz + (size_t)b * N * 3;

    __shared__ unsigned int hist[CELLS];     // 16 KiB
    __shared__ unsigned int waveS[16];

#pragma unroll
    for (int i = 0; i < CELLS / 1024; ++i) hist[i * 1024 + t] = 0;
    __syncthreads();

    int cell[16];
#pragma unroll
    for (int k = 0; k < 16; ++k) {
        const int n = k * 1024 + t;
        const float x = xb[n * 3 + 0];
        const float y = xb[n * 3 + 1];
        const float z = xb[n * 3 + 2];
        int cx = (int)(x * 16.0f); cx = cx < 0 ? 0 : (cx > 15 ? 15 : cx);
        int cy = (int)(y * 16.0f); cy = cy < 0 ? 0 : (cy > 15 ? 15 : cy);
        int cz = (int)(z * 16.0f); cz = cz < 0 ? 0 : (cz > 15 ? 15 : cz);
        cell[k] = spread3(cx) | (spread3(cy) << 1) | (spread3(cz) << 2);
        atomicAdd(&hist[cell[k]], 1u);
    }
    __syncthreads();

    const unsigned h0 = hist[4 * t + 0], h1 = hist[4 * t + 1],
                   h2 = hist[4 * t + 2], h3 = hist[4 * t + 3];
    const unsigned sum4 = h0 + h1 + h2 + h3;
    const int wid = t >> 6, lane = t & 63;
    unsigned inc = sum4;
#pragma unroll
    for (int off = 1; off < 64; off <<= 1) {
        const unsigned v = __shfl_up(inc, off);
        if (lane >= off) inc += v;
    }
    if (lane == 63) waveS[wid] = inc;
    __syncthreads();
    unsigned wbase = 0;
    {
        unsigned ws = (lane < 16) ? waveS[lane] : 0u;
        unsigned wi = ws;
#pragma unroll
        for (int off = 1; off < 16; off <<= 1) {
            const unsigned v = __shfl_up(wi, off);
            if (lane >= off) wi += v;
        }
        wbase = __shfl(wi - ws, wid);
    }
    const unsigned base = wbase + (inc - sum4);
    __syncthreads();
    hist[4 * t + 0] = base;
    hist[4 * t + 1] = base + h0;
    hist[4 * t + 2] = base + h0 + h1;
    hist[4 * t + 3] = base + h0 + h1 + h2;
    __syncthreads();

    float4* sb = (float4*)sorted + (size_t)b * N;
#pragma unroll
    for (int k = 0; k < 16; ++k) {
        const int n = k * 1024 + t;
        const float x = xb[n * 3 + 0];
        const float y = xb[n * 3 + 1];
        const float z = xb[n * 3 + 2];
        const unsigned pos = atomicAdd(&hist[cell[k]], 1u);
        sb[pos] = make_float4(x, y, z, (float)n);
    }
}

// ---------------- FPS with atomic-free work-queue compaction (r18) ----------------
// Per-point min-dist in LDS as plain f32 sd[N]; orig-n comes from sb[p].w.
// Step: A) owners bbox-test; ballot-enqueue passing segments (1 atomic/wave).
//       B) 16-lane rows process queued segments (4 segs/wave, packed waves):
//          plain sd read/modify/write + 4-level DPP row-reduce of u64 keys
//          (~bits(d)<<14 | n) -> lane 15 plain-writes segkey[seg]. NO atomics.
//       C) owners refresh cached (rkey,mval); 6-level DPP wave reduce + LDS
//          + 4-level block reduce -> far. Exact (max d, min n) tie-break
//          everywhere via u64-min keys.
// Skip soundness: bbox-dist^2 > mval*1.0001 (fp err ~3e-7) => no d can change.
// Chosen centroid's owner always executes (md2 = 0), so at s=0 mval=1e10
// forces ex=true for all (init rkey/mval never enter a reduce stale).
// CONVERGED STRUCTURE (rounds 16-24): data-path, math-width, reduce-shape,
// occupancy, barrier-count, prefetch, dense/sparse, multi-CU and multi-batch
// variants all measured equal or worse; residual cost is the 1023-step serial
// dependency chain (barriers + LDS round-trips + reduce + s_load latency).
__global__ __launch_bounds__(1024) void fps_kernel(const float* __restrict__ xyz,
                                                   const float* __restrict__ sorted,
                                                   float* out) {
#pragma clang fp contract(off)
    const int b = blockIdx.x;
    const int t = threadIdx.x;
    const float* xb = xyz + (size_t)b * N * 3;
    const float4* sb = (const float4*)sorted + (size_t)b * N;

    __shared__ float sd[N];                  // 64 KiB per-point min-dist
    __shared__ u64 segkey[1024];             // 8 KiB per-segment winner key
    __shared__ unsigned short queue[1024];   // 2 KiB
    __shared__ unsigned qc[2];
    __shared__ u64 swkey[2][16];

    const int wid = t >> 6;
    const int lane = t & 63;

    float lox = 1e30f, hix = -1e30f, loy = 1e30f, hiy = -1e30f, loz = 1e30f, hiz = -1e30f;
#pragma unroll
    for (int k = 0; k < 16; ++k) {
        const float4 v = sb[t * 16 + k];
        lox = fminf(lox, v.x); hix = fmaxf(hix, v.x);
        loy = fminf(loy, v.y); hiy = fmaxf(hiy, v.y);
        loz = fminf(loz, v.z); hiz = fmaxf(hiz, v.z);
        sd[t * 16 + k] = 1e10f;
    }
    if (t < 2) qc[t] = 0;
    u64 rkey = ~0ull;          // cached segment winner key (refreshed at s=0)
    float mval = 1e10f;        // cached max_k d[k] (forces ex at s=0)
    __syncthreads();

    float* nxo = out + OFF_NEWXYZ + (size_t)b * NPOINT * 3;
    int far = 0;

    for (int s = 0; s < NPOINT; ++s) {
        const int fs = __builtin_amdgcn_readfirstlane(far);
        const float cx = xb[fs * 3 + 0];
        const float cy = xb[fs * 3 + 1];
        const float cz = xb[fs * 3 + 2];
        if (t == 0) {
            nxo[s * 3 + 0] = cx;
            nxo[s * 3 + 1] = cy;
            nxo[s * 3 + 2] = cz;
        }
        if (s == NPOINT - 1) break;                  // last argmax is discarded

        // ---- A: bbox skip test + ballot enqueue (1 atomic per wave) ----
        const float ax = fmaxf(fmaxf(__fsub_rn(lox, cx), __fsub_rn(cx, hix)), 0.0f);
        const float ay = fmaxf(fmaxf(__fsub_rn(loy, cy), __fsub_rn(cy, hiy)), 0.0f);
        const float az = fmaxf(fmaxf(__fsub_rn(loz, cz), __fsub_rn(cz, hiz)), 0.0f);
        const float md2 = __fadd_rn(__fadd_rn(__fmul_rn(ax, ax), __fmul_rn(ay, ay)),
                                    __fmul_rn(az, az));
        const bool ex = !(md2 > __fmul_rn(mval, 1.0001f));
        if (t == 0) qc[(s + 1) & 1] = 0;
        {
            const u64 bal = __ballot(ex);
            unsigned wb = 0;
            if (lane == 0) wb = atomicAdd(&qc[s & 1], (unsigned)__popcll(bal));
            wb = __shfl(wb, 0);
            if (ex) {
                const unsigned pos = wb + (unsigned)__popcll(bal & ((1ull << lane) - 1ull));
                queue[pos] = (unsigned short)t;
            }
        }
        __syncthreads();

        // ---- B: packed segment-granular processing (16-lane row per segment) ----
        const unsigned nseg = qc[s & 1];
        const int row = t >> 4;         // 64 rows of 16 threads (= DPP rows)
        const int col = t & 15;
        for (unsigned j = (unsigned)row; j < nseg; j += 64) {
            const int seg = queue[j];
            const int p = (seg << 4) | col;
            const float4 v = sb[p];
            const float dx = __fsub_rn(v.x, cx);
            const float dy = __fsub_rn(v.y, cy);
            const float dz = __fsub_rn(v.z, cz);
            const float dist = __fadd_rn(
                __fadd_rn(__fmul_rn(dx, dx), __fmul_rn(dy, dy)),
                __fmul_rn(dz, dz));
            const float dnew = fminf(sd[p], dist);
            sd[p] = dnew;
            u64 key = ((u64)(unsigned)(~__float_as_uint(dnew)) << 14) |
                      (unsigned)(int)v.w;
            key = mindpp_u64<0x111>(key);   // row_shr:1  (within 16-lane row)
            key = mindpp_u64<0x112>(key);   // row_shr:2
            key = mindpp_u64<0x114>(key);   // row_shr:4
            key = mindpp_u64<0x118>(key);   // row_shr:8  -> lane 15 = row min
            if (col == 15) segkey[seg] = key;     // plain write, no atomic
        }
        __syncthreads();

        // ---- C: owners refresh cache; DPP wave + block u64-min reduce ----
        if (ex) {
            const u64 rk = segkey[t];
            rkey = rk;
            mval = __uint_as_float(~(unsigned)(rk >> 14));
        }
        u64 key = rkey;
        key = mindpp_u64<0x111>(key);   // row_shr:1
        key = mindpp_u64<0x112>(key);   // row_shr:2
        key = mindpp_u64<0x114>(key);   // row_shr:4
        key = mindpp_u64<0x118>(key);   // row_shr:8
        key = mindpp_u64<0x142>(key);   // row_bcast:15
        key = mindpp_u64<0x143>(key);   // row_bcast:31  -> lane 63 = wave min
        if (lane == 63) swkey[s & 1][wid] = key;
        __syncthreads();
        u64 kk = swkey[s & 1][lane & 15];
        kk = mindpp_u64<0x111>(kk);
        kk = mindpp_u64<0x112>(kk);
        kk = mindpp_u64<0x114>(kk);
        kk = mindpp_u64<0x118>(kk);
        const int lo15 = __builtin_amdgcn_readlane((int)(unsigned)(kk & 0xffffffffull), 15);
        far = lo15 & 16383;
    }
}

// ---------------- Ball query: one 64-lane wave per centroid ----------------
__global__ __launch_bounds__(256) void ballq_kernel(const float* __restrict__ xyz,
                                                    const float* __restrict__ radius_p,
                                                    float* out) {
    const int wib = threadIdx.x >> 6;
    const int lane = threadIdx.x & 63;
    const int gw = blockIdx.x * 4 + wib;   // 0..8191
    const int b = gw >> 10;
    const int s = gw & 1023;

    const float r = radius_p[0];
    const float r2 = __fmul_rn(r, r);

    const float* xb = xyz + (size_t)b * N * 3;
    const float* nx = out + OFF_NEWXYZ + (size_t)(b * NPOINT + s) * 3;
    const float c0 = nx[0], c1 = nx[1], c2 = nx[2];
    const float ss_s = __fadd_rn(__fadd_rn(__fmul_rn(c0, c0), __fmul_rn(c1, c1)),
                                 __fmul_rn(c2, c2));

    float* oidx = out + OFF_IDX + (size_t)(b * NPOINT + s) * NSAMPLE;
    float* ogx  = out + OFF_GXYZ + (size_t)(b * NPOINT + s) * NSAMPLE * 3;

    int filled = 0;
    int first = -1;
    for (int n0 = 0; n0 < N; n0 += 64) {
        const int n = n0 + lane;
        const float x = xb[n * 3 + 0];
        const float y = xb[n * 3 + 1];
        const float z = xb[n * 3 + 2];
        const float ssx = __fadd_rn(__fadd_rn(__fmul_rn(x, x), __fmul_rn(y, y)),
                                    __fmul_rn(z, z));
        const float dot = __fadd_rn(__fadd_rn(__fmul_rn(c0, x), __fmul_rn(c1, y)),
                                    __fmul_rn(c2, z));
        const float d2 = __fsub_rn(__fadd_rn(ss_s, ssx), __fmul_rn(2.0f, dot));
        const bool in = d2 < r2;
        const unsigned long long m = __ballot(in);
        if (first < 0 && m != 0ull) first = n0 + (int)__builtin_ctzll(m);
        if (in) {
            const int pos = filled + (int)__popcll(m & ((1ull << lane) - 1ull));
            if (pos < NSAMPLE) {
                oidx[pos] = (float)n;
                ogx[pos * 3 + 0] = __fsub_rn(x, c0);
                ogx[pos * 3 + 1] = __fsub_rn(y, c1);
                ogx[pos * 3 + 2] = __fsub_rn(z, c2);
            }
        }
        filled += (int)__popcll(m);
        if (filled >= NSAMPLE) break;
    }
    if (filled < NSAMPLE) {
        if (first < 0) first = 0;
        const float fx = xb[first * 3 + 0];
        const float fy = xb[first * 3 + 1];
        const float fz = xb[first * 3 + 2];
        const float g0 = __fsub_rn(fx, c0);
        const float g1 = __fsub_rn(fy, c1);
        const float g2 = __fsub_rn(fz, c2);
        for (int pos = filled + lane; pos < NSAMPLE; pos += 64) {
            oidx[pos] = (float)first;
            ogx[pos * 3 + 0] = g0;
            ogx[pos * 3 + 1] = g1;
            ogx[pos * 3 + 2] = g2;
        }
    }
}

// ---------------- new_points gather: one block per (b,s) ----------------
__global__ __launch_bounds__(256) void gather_kernel(const float* __restrict__ points,
                                                     float* out) {
    const int blk = blockIdx.x;            // b*NPOINT + s
    const int w = threadIdx.x >> 6;
    const int lane = threadIdx.x & 63;
    const int b = blk >> 10;

    const float* oidx = out + OFF_IDX + (size_t)blk * NSAMPLE;
    const float* pb = points + (size_t)b * N * CDIM;
    float* onp = out + OFF_NEWPTS + (size_t)blk * NSAMPLE * CDIM;

#pragma unroll
    for (int i = 0; i < 8; ++i) {
        const int slot = w * 8 + i;
        const int n = (int)oidx[slot];
        const float2 v = *(const float2*)(pb + (size_t)n * CDIM + lane * 2);
        *(float2*)(onp + (size_t)slot * CDIM + lane * 2) = v;
    }
}

extern "C" void kernel_launch(void* const* d_in, const int* in_sizes, int n_in,
                              void* d_out, int out_size, void* d_ws, size_t ws_size,
                              hipStream_t stream) {
    // inputs: [0]=npoint(int,1), [1]=radius(f32,1), [2]=xyz(f32, B*N*3), [3]=points(f32, B*N*CDIM)
    const float* xyz = (const float*)d_in[2];
    const float* points = (const float*)d_in[3];
    const float* radius = (const float*)d_in[1];
    float* out = (float*)d_out;

    // sorted AoS scratch lives in the new_points output region (2 MB of 134 MB);
    // gather_kernel fully overwrites it afterwards.
    float* sorted = out + OFF_NEWPTS;

    hipLaunchKernelGGL(sort_kernel, dim3(B), dim3(1024), 0, stream, xyz, sorted);
    hipLaunchKernelGGL(fps_kernel, dim3(B), dim3(1024), 0, stream, xyz, sorted, out);
    hipLaunchKernelGGL(ballq_kernel, dim3((B * NPOINT) / 4), dim3(256), 0, stream, xyz, radius, out);
    hipLaunchKernelGGL(gather_kernel, dim3(B * NPOINT), dim3(256), 0, stream, points, out);
}

// Round 26
// 1348.480 us; speedup vs baseline: 1.9632x; 1.1288x over previous
//
#include <hip/hip_runtime.h>

#define B 8
#define N 16384
#define NPOINT 1024
#define NSAMPLE 32
#define CDIM 128
#define CELLS 4096

// d_out layout (floats), reference return order:
// new_xyz [B,NPOINT,3], new_points [B,NPOINT,NSAMPLE,CDIM], idx [B,NPOINT,NSAMPLE], grouped_xyz [B,NPOINT,NSAMPLE,3]
#define OFF_NEWXYZ 0
#define OFF_NEWPTS (B * NPOINT * 3)                           // 24576
#define OFF_IDX    (OFF_NEWPTS + B * NPOINT * NSAMPLE * CDIM) // 33579008
#define OFF_GXYZ   (OFF_IDX + B * NPOINT * NSAMPLE)           // 33841152

typedef unsigned long long u64;

// u64-min DPP step: both halves shift coherently; invalid lanes keep old -> identity.
// row_shr:N operates WITHIN each 16-lane DPP row.
template <int CTRL>
__device__ __forceinline__ u64 mindpp_u64(u64 k) {
    const int lo = (int)(unsigned)(k & 0xffffffffull);
    const int hi = (int)(unsigned)(k >> 32);
    const int lo2 = __builtin_amdgcn_update_dpp(lo, lo, CTRL, 0xf, 0xf, false);
    const int hi2 = __builtin_amdgcn_update_dpp(hi, hi, CTRL, 0xf, 0xf, false);
    const u64 kt = ((u64)(unsigned)hi2 << 32) | (unsigned)lo2;
    return kt < k ? kt : k;
}

__device__ __forceinline__ int spread3(int v) {   // 4-bit -> bits 0,3,6,9
    return (v & 1) | ((v & 2) << 2) | ((v & 4) << 4) | ((v & 8) << 6);
}

// ---------- sort: Morton-bin each batch into AoS (x,y,z,(float)n) ----------
// Intra-cell order nondeterministic (atomicAdd) — harmless: all downstream
// reductions are (max d, min orig-n) exact, independent of storage order.
__global__ __launch_bounds__(1024) void sort_kernel(const float* __restrict__ xyz,
                                                    float* __restrict__ sorted) {
    const int b = blockIdx.x;
    const int t = threadIdx.x;
    const float* xb = xyz + (size_t)b * N * 3;

    __shared__ unsigned int hist[CELLS];     // 16 KiB
    __shared__ unsigned int waveS[16];

#pragma unroll
    for (int i = 0; i < CELLS / 1024; ++i) hist[i * 1024 + t] = 0;
    __syncthreads();

    int cell[16];
#pragma unroll
    for (int k = 0; k < 16; ++k) {
        const int n = k * 1024 + t;
        const float x = xb[n * 3 + 0];
        const float y = xb[n * 3 + 1];
        const float z = xb[n * 3 + 2];
        int cx = (int)(x * 16.0f); cx = cx < 0 ? 0 : (cx > 15 ? 15 : cx);
        int cy = (int)(y * 16.0f); cy = cy < 0 ? 0 : (cy > 15 ? 15 : cy);
        int cz = (int)(z * 16.0f); cz = cz < 0 ? 0 : (cz > 15 ? 15 : cz);
        cell[k] = spread3(cx) | (spread3(cy) << 1) | (spread3(cz) << 2);
        atomicAdd(&hist[cell[k]], 1u);
    }
    __syncthreads();

    const unsigned h0 = hist[4 * t + 0], h1 = hist[4 * t + 1],
                   h2 = hist[4 * t + 2], h3 = hist[4 * t + 3];
    const unsigned sum4 = h0 + h1 + h2 + h3;
    const int wid = t >> 6, lane = t & 63;
    unsigned inc = sum4;
#pragma unroll
    for (int off = 1; off < 64; off <<= 1) {
        const unsigned v = __shfl_up(inc, off);
        if (lane >= off) inc += v;
    }
    if (lane == 63) waveS[wid] = inc;
    __syncthreads();
    unsigned wbase = 0;
    {
        unsigned ws = (lane < 16) ? waveS[lane] : 0u;
        unsigned wi = ws;
#pragma unroll
        for (int off = 1; off < 16; off <<= 1) {
            const unsigned v = __shfl_up(wi, off);
            if (lane >= off) wi += v;
        }
        wbase = __shfl(wi - ws, wid);
    }
    const unsigned base = wbase + (inc - sum4);
    __syncthreads();
    hist[4 * t + 0] = base;
    hist[4 * t + 1] = base + h0;
    hist[4 * t + 2] = base + h0 + h1;
    hist[4 * t + 3] = base + h0 + h1 + h2;
    __syncthreads();

    float4* sb = (float4*)sorted + (size_t)b * N;
#pragma unroll
    for (int k = 0; k < 16; ++k) {
        const int n = k * 1024 + t;
        const float x = xb[n * 3 + 0];
        const float y = xb[n * 3 + 1];
        const float z = xb[n * 3 + 2];
        const unsigned pos = atomicAdd(&hist[cell[k]], 1u);
        sb[pos] = make_float4(x, y, z, (float)n);
    }
}

// ---------- FPS: r18 compaction with 2 barriers/step (register-carried reduce) ----------
// Per-point min-dist in LDS f32 sd[N]; exact (max d, min orig-n) tie-break via
// u64-min keys key = (~bits(d)<<14 | n).
// A(s): read cached segkey[t] (LDS, overlaps centroid s_load — both issued
//       before use), decode mval, bbox skip test, ballot enqueue.
// β1
// B(s): rows process queued segments; col-15 lane of each row accumulates the
//       fresh keys in REGISTER acc (no LDS round trip). End of B: contrib =
//       min(acc, ex ? ~0 : cached-rk) — exact because an ex segment's stale
//       key is <= its new key (d only decreases => key only increases), so it
//       MUST be excluded, and its fresh key is covered by acc of the row that
//       processed it; non-ex keys are unchanged since their last execution.
//       6-level DPP wave min -> lane63 writes swkey.
// β2  (also separates B(s)'s segkey/sd writes from A(s+1)'s reads)
// C(s): 4-level DPP block min over the 16 wave keys -> far.
// segkey[t] initialized to decode mval=1e10 so A(0) forces ex for all.
__global__ __launch_bounds__(1024) void fps_kernel(const float* __restrict__ xyz,
                                                   const float* __restrict__ sorted,
                                                   float* out) {
#pragma clang fp contract(off)
    const int b = blockIdx.x;
    const int t = threadIdx.x;
    const float* xb = xyz + (size_t)b * N * 3;
    const float4* sb = (const float4*)sorted + (size_t)b * N;

    __shared__ float sd[N];                  // 64 KiB per-point min-dist
    __shared__ u64 segkey[1024];             // 8 KiB per-segment winner key
    __shared__ unsigned short queue[1024];   // 2 KiB (single buffer: B(s) readers
                                             // finish before any A(s+1) writer)
    __shared__ unsigned qc[2];
    __shared__ u64 swkey[2][16];

    const int wid = t >> 6;
    const int lane = t & 63;

    float lox = 1e30f, hix = -1e30f, loy = 1e30f, hiy = -1e30f, loz = 1e30f, hiz = -1e30f;
#pragma unroll
    for (int k = 0; k < 16; ++k) {
        const float4 v = sb[t * 16 + k];
        lox = fminf(lox, v.x); hix = fmaxf(hix, v.x);
        loy = fminf(loy, v.y); hiy = fmaxf(hiy, v.y);
        loz = fminf(loz, v.z); hiz = fmaxf(hiz, v.z);
        sd[t * 16 + k] = 1e10f;
    }
    if (t < 2) qc[t] = 0;
    segkey[t] = ((u64)(unsigned)(~__float_as_uint(1e10f)) << 14);  // decodes mval=1e10
    __syncthreads();

    float* nxo = out + OFF_NEWXYZ + (size_t)b * NPOINT * 3;
    int far = 0;

    for (int s = 0; s < NPOINT; ++s) {
        // ---- A: cached-key LDS read overlapped with centroid s_load ----
        const u64 rk = segkey[t];                  // written latest in B(s-1), after β2
        const int fs = __builtin_amdgcn_readfirstlane(far);
        const float cx = xb[fs * 3 + 0];
        const float cy = xb[fs * 3 + 1];
        const float cz = xb[fs * 3 + 2];
        const float mval = __uint_as_float(~(unsigned)(rk >> 14));
        if (t == 0) {
            nxo[s * 3 + 0] = cx;
            nxo[s * 3 + 1] = cy;
            nxo[s * 3 + 2] = cz;
        }
        if (s == NPOINT - 1) break;                  // last argmax is discarded

        const float ax = fmaxf(fmaxf(__fsub_rn(lox, cx), __fsub_rn(cx, hix)), 0.0f);
        const float ay = fmaxf(fmaxf(__fsub_rn(loy, cy), __fsub_rn(cy, hiy)), 0.0f);
        const float az = fmaxf(fmaxf(__fsub_rn(loz, cz), __fsub_rn(cz, hiz)), 0.0f);
        const float md2 = __fadd_rn(__fadd_rn(__fmul_rn(ax, ax), __fmul_rn(ay, ay)),
                                    __fmul_rn(az, az));
        const bool ex = !(md2 > __fmul_rn(mval, 1.0001f));
        if (t == 0) qc[(s + 1) & 1] = 0;
        {
            const u64 bal = __ballot(ex);
            unsigned wb = 0;
            if (lane == 0) wb = atomicAdd(&qc[s & 1], (unsigned)__popcll(bal));
            wb = __shfl(wb, 0);
            if (ex) {
                const unsigned pos = wb + (unsigned)__popcll(bal & ((1ull << lane) - 1ull));
                queue[pos] = (unsigned short)t;
            }
        }
        __syncthreads();                             // β1: queue ready

        // ---- B: packed segment processing + register-carried key accumulation ----
        const unsigned nseg = qc[s & 1];
        const int row = t >> 4;         // 64 rows of 16 threads (= DPP rows)
        const int col = t & 15;
        u64 acc = ~0ull;
        for (unsigned j = (unsigned)row; j < nseg; j += 64) {
            const int seg = queue[j];
            const int p = (seg << 4) | col;
            const float4 v = sb[p];
            const float dx = __fsub_rn(v.x, cx);
            const float dy = __fsub_rn(v.y, cy);
            const float dz = __fsub_rn(v.z, cz);
            const float dist = __fadd_rn(
                __fadd_rn(__fmul_rn(dx, dx), __fmul_rn(dy, dy)),
                __fmul_rn(dz, dz));
            const float dnew = fminf(sd[p], dist);
            sd[p] = dnew;
            u64 key = ((u64)(unsigned)(~__float_as_uint(dnew)) << 14) |
                      (unsigned)(int)v.w;
            key = mindpp_u64<0x111>(key);   // row_shr:1  (within 16-lane row)
            key = mindpp_u64<0x112>(key);   // row_shr:2
            key = mindpp_u64<0x114>(key);   // row_shr:4
            key = mindpp_u64<0x118>(key);   // row_shr:8  -> lane 15 = row min
            if (col == 15) {
                segkey[seg] = key;                 // plain write; read in A(s+1)
                acc = key < acc ? key : acc;       // register accumulation
            }
        }
        // combine: fresh keys (acc) + cached keys of non-ex segments
        u64 key = ex ? acc : (rk < acc ? rk : acc);
        key = mindpp_u64<0x111>(key);   // row_shr:1
        key = mindpp_u64<0x112>(key);   // row_shr:2
        key = mindpp_u64<0x114>(key);   // row_shr:4
        key = mindpp_u64<0x118>(key);   // row_shr:8
        key = mindpp_u64<0x142>(key);   // row_bcast:15
        key = mindpp_u64<0x143>(key);   // row_bcast:31  -> lane 63 = wave min
        if (lane == 63) swkey[s & 1][wid] = key;
        __syncthreads();                             // β2: swkey + segkey/sd ready

        // ---- C: block u64-min over 16 wave keys ----
        u64 kk = swkey[s & 1][lane & 15];
        kk = mindpp_u64<0x111>(kk);
        kk = mindpp_u64<0x112>(kk);
        kk = mindpp_u64<0x114>(kk);
        kk = mindpp_u64<0x118>(kk);
        const int lo15 = __builtin_amdgcn_readlane((int)(unsigned)(kk & 0xffffffffull), 15);
        far = lo15 & 16383;
    }
}

// ---------------- Ball query: one 64-lane wave per centroid ----------------
__global__ __launch_bounds__(256) void ballq_kernel(const float* __restrict__ xyz,
                                                    const float* __restrict__ radius_p,
                                                    float* out) {
    const int wib = threadIdx.x >> 6;
    const int lane = threadIdx.x & 63;
    const int gw = blockIdx.x * 4 + wib;   // 0..8191
    const int b = gw >> 10;
    const int s = gw & 1023;

    const float r = radius_p[0];
    const float r2 = __fmul_rn(r, r);

    const float* xb = xyz + (size_t)b * N * 3;
    const float* nx = out + OFF_NEWXYZ + (size_t)(b * NPOINT + s) * 3;
    const float c0 = nx[0], c1 = nx[1], c2 = nx[2];
    const float ss_s = __fadd_rn(__fadd_rn(__fmul_rn(c0, c0), __fmul_rn(c1, c1)),
                                 __fmul_rn(c2, c2));

    float* oidx = out + OFF_IDX + (size_t)(b * NPOINT + s) * NSAMPLE;
    float* ogx  = out + OFF_GXYZ + (size_t)(b * NPOINT + s) * NSAMPLE * 3;

    int filled = 0;
    int first = -1;
    for (int n0 = 0; n0 < N; n0 += 64) {
        const int n = n0 + lane;
        const float x = xb[n * 3 + 0];
        const float y = xb[n * 3 + 1];
        const float z = xb[n * 3 + 2];
        const float ssx = __fadd_rn(__fadd_rn(__fmul_rn(x, x), __fmul_rn(y, y)),
                                    __fmul_rn(z, z));
        const float dot = __fadd_rn(__fadd_rn(__fmul_rn(c0, x), __fmul_rn(c1, y)),
                                    __fmul_rn(c2, z));
        const float d2 = __fsub_rn(__fadd_rn(ss_s, ssx), __fmul_rn(2.0f, dot));
        const bool in = d2 < r2;
        const unsigned long long m = __ballot(in);
        if (first < 0 && m != 0ull) first = n0 + (int)__builtin_ctzll(m);
        if (in) {
            const int pos = filled + (int)__popcll(m & ((1ull << lane) - 1ull));
            if (pos < NSAMPLE) {
                oidx[pos] = (float)n;
                ogx[pos * 3 + 0] = __fsub_rn(x, c0);
                ogx[pos * 3 + 1] = __fsub_rn(y, c1);
                ogx[pos * 3 + 2] = __fsub_rn(z, c2);
            }
        }
        filled += (int)__popcll(m);
        if (filled >= NSAMPLE) break;
    }
    if (filled < NSAMPLE) {
        if (first < 0) first = 0;
        const float fx = xb[first * 3 + 0];
        const float fy = xb[first * 3 + 1];
        const float fz = xb[first * 3 + 2];
        const float g0 = __fsub_rn(fx, c0);
        const float g1 = __fsub_rn(fy, c1);
        const float g2 = __fsub_rn(fz, c2);
        for (int pos = filled + lane; pos < NSAMPLE; pos += 64) {
            oidx[pos] = (float)first;
            ogx[pos * 3 + 0] = g0;
            ogx[pos * 3 + 1] = g1;
            ogx[pos * 3 + 2] = g2;
        }
    }
}

// ---------------- new_points gather: one block per (b,s) ----------------
__global__ __launch_bounds__(256) void gather_kernel(const float* __restrict__ points,
                                                     float* out) {
    const int blk = blockIdx.x;            // b*NPOINT + s
    const int w = threadIdx.x >> 6;
    const int lane = threadIdx.x & 63;
    const int b = blk >> 10;

    const float* oidx = out + OFF_IDX + (size_t)blk * NSAMPLE;
    const float* pb = points + (size_t)b * N * CDIM;
    float* onp = out + OFF_NEWPTS + (size_t)blk * NSAMPLE * CDIM;

#pragma unroll
    for (int i = 0; i < 8; ++i) {
        const int slot = w * 8 + i;
        const int n = (int)oidx[slot];
        const float2 v = *(const float2*)(pb + (size_t)n * CDIM + lane * 2);
        *(float2*)(onp + (size_t)slot * CDIM + lane * 2) = v;
    }
}

extern "C" void kernel_launch(void* const* d_in, const int* in_sizes, int n_in,
                              void* d_out, int out_size, void* d_ws, size_t ws_size,
                              hipStream_t stream) {
    // inputs: [0]=npoint(int,1), [1]=radius(f32,1), [2]=xyz(f32, B*N*3), [3]=points(f32, B*N*CDIM)
    const float* xyz = (const float*)d_in[2];
    const float* points = (const float*)d_in[3];
    const float* radius = (const float*)d_in[1];
    float* out = (float*)d_out;

    // sorted AoS scratch lives in the new_points output region (2 MB of 134 MB);
    // gather_kernel fully overwrites it afterwards.
    float* sorted = out + OFF_NEWPTS;

    hipLaunchKernelGGL(sort_kernel, dim3(B), dim3(1024), 0, stream, xyz, sorted);
    hipLaunchKernelGGL(fps_kernel, dim3(B), dim3(1024), 0, stream, xyz, sorted, out);
    hipLaunchKernelGGL(ballq_kernel, dim3((B * NPOINT) / 4), dim3(256), 0, stream, xyz, radius, out);
    hipLaunchKernelGGL(gather_kernel, dim3(B * NPOINT), dim3(256), 0, stream, points, out);
}